// Round 6
// baseline (4194.246 us; speedup 1.0000x reference)
//
#include <hip/hip_runtime.h>
#include <math.h>

// GRU decoder w/ attention.
//  - recurrence stays f32 (error-amplifying: do not touch numerics)
//  - logits GEMM: bf16 MFMA, 2-term hi/lo split (post-recurrence, safe)
//  - 3 kernels/step: S1(q+attn | gh), S2(gi), S3(gate+LN)
//  - shared 1024-thread 64x64-tile f32 GEMM for kv/Wfused/giE/h0
// Dims: B=64 N=49 ENC=2048 D=A=512 H=8 hd=64 T=20 V=32000 G3=1536

#define TSTEPS 20
#define AS_LD 65
#define BS_LD 68

// ---------------- ws layout (float offsets) ----------------
#define OFF_ME      0u          // 64*2048            = 131072
#define OFF_EMB     131072u     // 1280*512           = 655360
#define OFF_KT      786432u     // 64*8*64*49         = 1605632
#define OFF_V       2392064u    // 3136*512           = 1605632
#define OFF_GIE     3997696u    // 1280*1536          = 1966080
#define OFF_WF      5963776u    // 512*1536           = 786432
#define OFF_GIBO    6750208u    // 1536
#define OFF_H       6751744u    // 64*512             = 32768
#define OFF_GHP     6784512u    // 64*1536            = 98304
#define OFF_GIP     6882816u    // 64*1536            = 98304
#define OFF_CTX     6981120u    // 64*512             = 32768
#define OFF_HALLH   7013888u    // 1280*512 ushort    = 327680 floats
#define OFF_HALLL   7341568u    // 1280*512 ushort    = 327680 floats
#define OFF_FCH     7669248u    // 32000*512 ushort   = 8192000 floats
// end = 15861248 floats = 63.4 MB

typedef __bf16 bf16x8 __attribute__((ext_vector_type(8)));
typedef float f32x4 __attribute__((ext_vector_type(4)));

__device__ __forceinline__ unsigned short f2bf(float x) {
    unsigned u = __float_as_uint(x);
    unsigned r = (u + 0x7fffu + ((u >> 16) & 1u)) >> 16;
    return (unsigned short)r;
}
__device__ __forceinline__ float bf2f(unsigned short h) {
    return __uint_as_float(((unsigned)h) << 16);
}

__device__ __forceinline__ void gload16(const void* g, void* l) {
    __builtin_amdgcn_global_load_lds(
        (const __attribute__((address_space(1))) unsigned int*)g,
        (__attribute__((address_space(3))) unsigned int*)l, 16, 0, 0);
}

// ---------------- small one-time kernels ----------------

__global__ void mean_kernel(const float* __restrict__ enc, float* __restrict__ me) {
    int i = blockIdx.x * 256 + threadIdx.x;       // 64*2048
    int b = i >> 11, e = i & 2047;
    const float* p = enc + (size_t)b * 49 * 2048 + e;
    float s = 0.f;
    #pragma unroll 7
    for (int n = 0; n < 49; n++) s += p[n * 2048];
    me[i] = s * (1.0f / 49.0f);
}

__global__ void init_kernel(const int* __restrict__ captions, const float* __restrict__ emb_w,
                            float* __restrict__ embAll, float* __restrict__ attw) {
    int i = blockIdx.x * 256 + threadIdx.x;       // 1280*512
    int t = i >> 15;
    int b = (i >> 9) & 63;
    int e = i & 511;
    int tok = captions[b * 21 + t];
    embAll[i] = emb_w[(size_t)tok * 512 + e];
    if (i < 62720) attw[i] = 0.f;
}

__global__ void gibo_kernel(const float* __restrict__ W_ih, const float* __restrict__ bo,
                            float* __restrict__ gibo) {
    int j = blockIdx.x, tid = threadIdx.x;        // 1536 blocks x 256
    const float* w = W_ih + (size_t)j * 2560 + 512;
    float s = 0.f;
    for (int e = tid; e < 2048; e += 256) s += w[e] * bo[e];
    for (int o = 32; o; o >>= 1) s += __shfl_xor(s, o);
    __shared__ float r[4];
    if ((tid & 63) == 0) r[tid >> 6] = s;
    __syncthreads();
    if (tid == 0) gibo[j] = r[0] + r[1] + r[2] + r[3];
}

__global__ void conv_fc(const float* __restrict__ fc, unsigned short* __restrict__ outp) {
    int i = (blockIdx.x * 256 + threadIdx.x) * 4;   // 16384000 elems
    float4 v = *(const float4*)(fc + i);
    unsigned h0 = f2bf(v.x), h1 = f2bf(v.y), h2 = f2bf(v.z), h3 = f2bf(v.w);
    uint2 o;
    o.x = h0 | (h1 << 16);
    o.y = h2 | (h3 << 16);
    *(uint2*)(outp + i) = o;
}

// ---------------- shared f32 64x64-tile GEMM (1024 threads) ----------------
// C tile = A[m0:m0+64, :K] * B ; bt=0: B[k][n], bt=1: B[n][k]

__device__ __forceinline__ void gemm_tile_1024(
    const float* __restrict__ A, int lda, int m0,
    const float* __restrict__ B, int ldb, int bt, int n0, int K,
    float* As, float* Bs, float acc[4]) {
    int tid = threadIdx.x;
    int r = tid & 63, c0 = (tid >> 6) * 4;
    acc[0] = acc[1] = acc[2] = acc[3] = 0.f;
    for (int k0 = 0; k0 < K; k0 += 64) {
        {
            int m = tid >> 4, kq = (tid & 15) * 4;
            float4 av = *(const float4*)(A + (size_t)(m0 + m) * lda + k0 + kq);
            As[(kq + 0) * AS_LD + m] = av.x;
            As[(kq + 1) * AS_LD + m] = av.y;
            As[(kq + 2) * AS_LD + m] = av.z;
            As[(kq + 3) * AS_LD + m] = av.w;
        }
        if (bt == 0) {
            int k = tid >> 4, nq = (tid & 15) * 4;
            *(float4*)&Bs[k * BS_LD + nq] =
                *(const float4*)(B + (size_t)(k0 + k) * ldb + n0 + nq);
        } else {
            int n = tid >> 4, kq = (tid & 15) * 4;
            float4 bv = *(const float4*)(B + (size_t)(n0 + n) * ldb + k0 + kq);
            Bs[(kq + 0) * BS_LD + n] = bv.x;
            Bs[(kq + 1) * BS_LD + n] = bv.y;
            Bs[(kq + 2) * BS_LD + n] = bv.z;
            Bs[(kq + 3) * BS_LD + n] = bv.w;
        }
        __syncthreads();
        #pragma unroll 8
        for (int k = 0; k < 64; k++) {
            float a = As[k * AS_LD + r];
            float4 b4 = *(const float4*)&Bs[k * BS_LD + c0];
            acc[0] += a * b4.x;
            acc[1] += a * b4.y;
            acc[2] += a * b4.z;
            acc[3] += a * b4.w;
        }
        __syncthreads();
    }
}

// emode: 0 plain(+bias), 2 kt scatter (row=b*49+nn -> [b*8+h][d][nn], +bias)
__global__ __launch_bounds__(1024) void gemm64f(
    const float* __restrict__ A, int lda,
    const float* __restrict__ B, int ldb, int bt,
    const float* __restrict__ bias,
    float* __restrict__ C, int ldc, int K, int emode) {
    __shared__ float As[64 * AS_LD];
    __shared__ float Bs[64 * BS_LD];
    int m0 = blockIdx.y * 64, n0 = blockIdx.x * 64;
    float acc[4];
    gemm_tile_1024(A, lda, m0, B, ldb, bt, n0, K, As, Bs, acc);
    int tid = threadIdx.x;
    int r = tid & 63, c0 = (tid >> 6) * 4;
    int gm = m0 + r;
    if (emode == 0) {
        float4 o;
        o.x = acc[0] + (bias ? bias[n0 + c0 + 0] : 0.f);
        o.y = acc[1] + (bias ? bias[n0 + c0 + 1] : 0.f);
        o.z = acc[2] + (bias ? bias[n0 + c0 + 2] : 0.f);
        o.w = acc[3] + (bias ? bias[n0 + c0 + 3] : 0.f);
        *(float4*)(C + (size_t)gm * ldc + n0 + c0) = o;
    } else {
        int bb = gm / 49, nn2 = gm - bb * 49;
        #pragma unroll
        for (int j = 0; j < 4; j++) {
            int col = n0 + c0 + j;
            int hh = col >> 6, dd = col & 63;
            C[((size_t)(bb * 8 + hh) * 64 + dd) * 49 + nn2] = acc[j] + bias[col];
        }
    }
}

// ---------------- recurrence step kernels ----------------

// blocks 0..7: q-head tile + attention epilogue; blocks 8..31: gh tile
__global__ __launch_bounds__(1024) void step1_kernel(
    const float* __restrict__ h, const float* __restrict__ Wq, const float* __restrict__ bq,
    const float* __restrict__ Whh, const float* __restrict__ ktb, const float* __restrict__ vb,
    float* __restrict__ ctx, float* __restrict__ ghp, float* __restrict__ attw, int t) {
    __shared__ float As[64 * AS_LD];
    __shared__ float Bs[64 * BS_LD];
    __shared__ float qs[64 * 65];
    __shared__ float al[64 * 52];
    int blk = blockIdx.x, tid = threadIdx.x;
    float acc[4];
    if (blk >= 8) {
        int n0 = (blk - 8) * 64;
        gemm_tile_1024(h, 512, 0, Whh, 512, 1, n0, 512, As, Bs, acc);
        int r = tid & 63, c0 = (tid >> 6) * 4;
        float4 o = make_float4(acc[0], acc[1], acc[2], acc[3]);
        *(float4*)(ghp + (size_t)r * 1536 + n0 + c0) = o;
        return;
    }
    int hh = blk;
    gemm_tile_1024(h, 512, 0, Wq, 512, 0, hh * 64, 512, As, Bs, acc);
    {
        int r = tid & 63, c0 = (tid >> 6) * 4;
        #pragma unroll
        for (int j = 0; j < 4; j++) qs[r * 65 + c0 + j] = acc[j] + bq[hh * 64 + c0 + j];
    }
    __syncthreads();
    // scores + softmax: 16 threads per batch row
    {
        int b = tid >> 4, jj = tid & 15;
        float sv[4];
        int nn[4];
        int cnt = 0;
        #pragma unroll
        for (int i = 0; i < 4; i++) {
            int n = jj + 16 * i;
            if (n < 49) { nn[cnt] = n; sv[cnt] = 0.f; cnt++; }
        }
        const float* kpb = ktb + ((size_t)(b * 8 + hh) * 64) * 49;
        for (int d = 0; d < 64; d++) {
            float qv = qs[b * 65 + d];
            const float* kp = kpb + d * 49;
            for (int c = 0; c < cnt; c++) sv[c] += qv * kp[nn[c]];
        }
        float mx = -1e30f;
        for (int c = 0; c < cnt; c++) { sv[c] *= 0.125f; mx = fmaxf(mx, sv[c]); }
        for (int o = 8; o; o >>= 1) mx = fmaxf(mx, __shfl_xor(mx, o));
        float sm = 0.f;
        for (int c = 0; c < cnt; c++) { sv[c] = expf(sv[c] - mx); sm += sv[c]; }
        for (int o = 8; o; o >>= 1) sm += __shfl_xor(sm, o);
        float inv = 1.f / sm;
        for (int c = 0; c < cnt; c++) {
            float a = sv[c] * inv;
            al[b * 52 + nn[c]] = a;
            atomicAdd(&attw[(size_t)(b * TSTEPS + t) * 49 + nn[c]], a * 0.125f);
        }
    }
    __syncthreads();
    // ctx = alpha @ v for this head
    {
        int d = tid & 63, bg = tid >> 6;  // bg 0..15
        #pragma unroll
        for (int bb = 0; bb < 4; bb++) {
            int b2 = bg * 4 + bb;
            const float* vp = vb + (size_t)b2 * 49 * 512 + hh * 64 + d;
            const float* alp = al + b2 * 52;
            float c = 0.f;
            #pragma unroll 7
            for (int n = 0; n < 49; n++) c += alp[n] * vp[(size_t)n * 512];
            ctx[b2 * 512 + hh * 64 + d] = c;
        }
    }
}

// gates + LayerNorm; also emits bf16 hi/lo of h_ln for the logits MFMA
__global__ __launch_bounds__(512) void gate_ln_kernel(
    const float* __restrict__ gip, const float* __restrict__ ghp,
    const float* __restrict__ giE, const float* __restrict__ gibo,
    const float* __restrict__ b_ih, const float* __restrict__ b_hh,
    const float* __restrict__ ln_g, const float* __restrict__ ln_b,
    float* __restrict__ h, unsigned short* __restrict__ hallH,
    unsigned short* __restrict__ hallL, int t) {
    int b = blockIdx.x, d = threadIdx.x;
    const float* gie = giE + (size_t)(t * 64 + b) * 1536;
    const float* gp = gip + (size_t)b * 1536;
    const float* hp = ghp + (size_t)b * 1536;
    float g0 = gp[d] + gie[d] + b_ih[d] + gibo[d];
    float g1 = gp[512 + d] + gie[512 + d] + b_ih[512 + d] + gibo[512 + d];
    float g2 = gp[1024 + d] + gie[1024 + d] + b_ih[1024 + d] + gibo[1024 + d];
    float e0 = hp[d] + b_hh[d];
    float e1 = hp[512 + d] + b_hh[512 + d];
    float e2 = hp[1024 + d] + b_hh[1024 + d];
    float r = 1.f / (1.f + expf(-(g0 + e0)));
    float z = 1.f / (1.f + expf(-(g1 + e1)));
    float nn = tanhf(g2 + r * e2);
    float hprev = h[b * 512 + d];
    float hn = (1.f - z) * nn + z * hprev;
    __shared__ float red[8];
    float x = hn;
    for (int o = 32; o; o >>= 1) x += __shfl_xor(x, o);
    if ((d & 63) == 0) red[d >> 6] = x;
    __syncthreads();
    float mu = 0.f;
    #pragma unroll
    for (int i = 0; i < 8; i++) mu += red[i];
    mu *= (1.f / 512.f);
    __syncthreads();
    float c = hn - mu;
    x = c * c;
    for (int o = 32; o; o >>= 1) x += __shfl_xor(x, o);
    if ((d & 63) == 0) red[d >> 6] = x;
    __syncthreads();
    float var = 0.f;
    #pragma unroll
    for (int i = 0; i < 8; i++) var += red[i];
    var *= (1.f / 512.f);
    float hl = c * rsqrtf(var + 1e-5f) * ln_g[d] + ln_b[d];
    h[b * 512 + d] = hl;
    unsigned short hi = f2bf(hl);
    hallH[(size_t)(t * 64 + b) * 512 + d] = hi;
    hallL[(size_t)(t * 64 + b) * 512 + d] = f2bf(hl - bf2f(hi));
}

// ---------------- logits: bf16 MFMA, 2-term hi/lo, K_eff=1024 ----------------
// C[(b*20+t)][n] = h_all[t*64+b][:] @ fcT[n][:] + fc_b[n]
__global__ __launch_bounds__(256) void logits_mfma(
    const unsigned short* __restrict__ Ahi, const unsigned short* __restrict__ Alo,
    const unsigned short* __restrict__ Bhi, const float* __restrict__ bias,
    float* __restrict__ out) {
    __shared__ __align__(16) short As[128 * 64];
    __shared__ __align__(16) short Bs[128 * 64];
    int tid = threadIdx.x;
    int wid = tid >> 6, lane = tid & 63;
    int n0 = blockIdx.x * 128, m0 = blockIdx.y * 128;
    f32x4 acc[4][4] = {};
    int wm = (wid >> 1) * 64, wn = (wid & 1) * 64;
    int crow = lane & 15;
    int koff8 = (lane >> 4) * 8;
    for (int k0e = 0; k0e < 1024; k0e += 64) {
        const unsigned short* Ab = (k0e & 512) ? Alo : Ahi;
        int koff = k0e & 511;
        #pragma unroll
        for (int c = 0; c < 4; c++) {
            int chunk = wid * 4 + c;
            int off = chunk * 512 + lane * 8;
            int row = off >> 6, col = off & 63;
            gload16(Ab + (size_t)(m0 + row) * 512 + koff + col, &As[chunk * 512]);
            gload16(Bhi + (size_t)(n0 + row) * 512 + koff + col, &Bs[chunk * 512]);
        }
        __syncthreads();
        #pragma unroll
        for (int ks = 0; ks < 2; ks++) {
            bf16x8 af[4], bfm[4];
            #pragma unroll
            for (int i = 0; i < 4; i++)
                af[i] = *(const bf16x8*)&As[(wm + i * 16 + crow) * 64 + ks * 32 + koff8];
            #pragma unroll
            for (int j = 0; j < 4; j++)
                bfm[j] = *(const bf16x8*)&Bs[(wn + j * 16 + crow) * 64 + ks * 32 + koff8];
            #pragma unroll
            for (int i = 0; i < 4; i++)
                #pragma unroll
                for (int j = 0; j < 4; j++)
                    acc[i][j] = __builtin_amdgcn_mfma_f32_16x16x32_bf16(
                        af[i], bfm[j], acc[i][j], 0, 0, 0);
        }
        __syncthreads();
    }
    int r4 = (lane >> 4) * 4;
    #pragma unroll
    for (int i = 0; i < 4; i++) {
        #pragma unroll
        for (int j = 0; j < 4; j++) {
            int col = n0 + wn + j * 16 + (lane & 15);
            float bv = bias[col];
            #pragma unroll
            for (int r = 0; r < 4; r++) {
                int gm = m0 + wm + i * 16 + r4 + r;
                int orow = (gm & 63) * TSTEPS + (gm >> 6);
                out[(size_t)orow * 32000 + col] = acc[i][j][r] + bv;
            }
        }
    }
}

// ---------------- launcher ----------------

extern "C" void kernel_launch(void* const* d_in, const int* in_sizes, int n_in,
                              void* d_out, int out_size, void* d_ws, size_t ws_size,
                              hipStream_t stream) {
    const float* enc    = (const float*)d_in[0];
    const int*   caps   = (const int*)d_in[1];
    const float* emb_w  = (const float*)d_in[2];
    const float* Wq     = (const float*)d_in[3];
    const float* bq     = (const float*)d_in[4];
    const float* Wk     = (const float*)d_in[5];
    const float* bk     = (const float*)d_in[6];
    const float* Wv     = (const float*)d_in[7];
    const float* bv     = (const float*)d_in[8];
    const float* Wo     = (const float*)d_in[9];
    const float* bo     = (const float*)d_in[10];
    const float* init_w = (const float*)d_in[11];
    const float* init_b = (const float*)d_in[12];
    const float* W_ih   = (const float*)d_in[13];
    const float* b_ih   = (const float*)d_in[14];
    const float* W_hh   = (const float*)d_in[15];
    const float* b_hh   = (const float*)d_in[16];
    const float* ln_g   = (const float*)d_in[17];
    const float* ln_b   = (const float*)d_in[18];
    const float* fc_w   = (const float*)d_in[19];
    const float* fc_b   = (const float*)d_in[20];

    float* ws     = (float*)d_ws;
    float* me     = ws + OFF_ME;
    float* embAll = ws + OFF_EMB;
    float* ktb    = ws + OFF_KT;
    float* vb     = ws + OFF_V;
    float* giE    = ws + OFF_GIE;
    float* Wfused = ws + OFF_WF;
    float* gibo   = ws + OFF_GIBO;
    float* h      = ws + OFF_H;
    float* ghp    = ws + OFF_GHP;
    float* gip    = ws + OFF_GIP;
    float* ctx    = ws + OFF_CTX;
    unsigned short* hallH = (unsigned short*)(ws + OFF_HALLH);
    unsigned short* hallL = (unsigned short*)(ws + OFF_HALLL);
    unsigned short* fcH   = (unsigned short*)(ws + OFF_FCH);

    float* out  = (float*)d_out;          // [64][20][32000]
    float* attw = out + 40960000;         // [64][20][49]

    // ---- one-time precompute ----
    hipLaunchKernelGGL(mean_kernel, dim3(512), dim3(256), 0, stream, enc, me);
    hipLaunchKernelGGL(init_kernel, dim3(2560), dim3(256), 0, stream, caps, emb_w, embAll, attw);
    hipLaunchKernelGGL(gibo_kernel, dim3(1536), dim3(256), 0, stream, W_ih, bo, gibo);
    hipLaunchKernelGGL(conv_fc, dim3(16000), dim3(256), 0, stream, fc_w, fcH);
    // h0 = mean(enc) @ init_w.T + init_b
    hipLaunchKernelGGL(gemm64f, dim3(8, 1), dim3(1024), 0, stream,
                       me, 2048, init_w, 2048, 1, init_b, h, 512, 2048, 0);
    // k (scattered to kt[b*8+h][d][n]) and v
    hipLaunchKernelGGL(gemm64f, dim3(8, 49), dim3(1024), 0, stream,
                       enc, 2048, Wk, 512, 0, bk, ktb, 0, 2048, 2);
    hipLaunchKernelGGL(gemm64f, dim3(8, 49), dim3(1024), 0, stream,
                       enc, 2048, Wv, 512, 0, bv, vb, 512, 2048, 0);
    // giE = embAll @ W_ih[:, :512].T
    hipLaunchKernelGGL(gemm64f, dim3(24, 20), dim3(1024), 0, stream,
                       embAll, 512, W_ih, 2560, 1, (const float*)nullptr, giE, 1536, 512, 0);
    // Wfused = Wo @ W_ih[:, 512:].T
    hipLaunchKernelGGL(gemm64f, dim3(24, 8), dim3(1024), 0, stream,
                       Wo, 2048, W_ih + 512, 2560, 1, (const float*)nullptr, Wfused, 1536, 2048, 0);

    // ---- recurrence: 3 kernels/step ----
    for (int t = 0; t < TSTEPS; t++) {
        hipLaunchKernelGGL(step1_kernel, dim3(32), dim3(1024), 0, stream,
                           h, Wq, bq, W_hh, ktb, vb, ctx, ghp, attw, t);
        hipLaunchKernelGGL(gemm64f, dim3(24, 1), dim3(1024), 0, stream,
                           ctx, 512, Wfused, 1536, 0, (const float*)nullptr, gip, 1536, 512, 0);
        hipLaunchKernelGGL(gate_ln_kernel, dim3(64), dim3(512), 0, stream,
                           gip, ghp, giE, gibo, b_ih, b_hh, ln_g, ln_b, h, hallH, hallL, t);
    }

    // ---- batched logits via bf16 MFMA ----
    hipLaunchKernelGGL(logits_mfma, dim3(250, 10), dim3(256), 0, stream,
                       hallH, hallL, fcH, fc_b, out);
}